// Round 4
// baseline (463.229 us; speedup 1.0000x reference)
//
#include <hip/hip_runtime.h>

typedef unsigned short ushort_t;
typedef unsigned long long u64_t;
typedef __attribute__((ext_vector_type(8))) short v8bf;
typedef __attribute__((ext_vector_type(8))) unsigned short v8us;
typedef __attribute__((ext_vector_type(4))) float v4f;

#define BROWS 4096
#define DIMK 256
#define QN 32768
#define EXPSCALE 14.426950408889634f   // 10 * log2(e)

__device__ __forceinline__ ushort_t f2bf(float f) {
    unsigned u = __float_as_uint(f);
    return (ushort_t)((u + 0x7FFFu + ((u >> 16) & 1u)) >> 16);   // RNE
}
__device__ __forceinline__ unsigned enc_f32(float f) {
    unsigned b = __float_as_uint(f);
    return b ^ ((unsigned)(((int)b) >> 31) | 0x80000000u);
}
__device__ __forceinline__ u64_t shfl_xor_u64(u64_t v, int off) {
    unsigned lo = (unsigned)(v & 0xFFFFFFFFull);
    unsigned hi = (unsigned)(v >> 32);
    lo = (unsigned)__shfl_xor((int)lo, off, 64);
    hi = (unsigned)__shfl_xor((int)hi, off, 64);
    return ((u64_t)hi << 32) | (u64_t)lo;
}
#define GLOAD(g, l_) __builtin_amdgcn_global_load_lds(                         \
    (const __attribute__((address_space(1))) void*)(g),                        \
    (__attribute__((address_space(3))) void*)(l_), 16, 0, 0)

// ---- bf16 conversion of the queue ----
__global__ __launch_bounds__(256) void conv_bf16(const float* __restrict__ in,
                                                 ushort_t* __restrict__ out) {
    const size_t i = ((size_t)blockIdx.x * 256 + threadIdx.x) * 8;
    float4 x = *(const float4*)&in[i];
    float4 y = *(const float4*)&in[i + 4];
    v8us o;
    o[0] = f2bf(x.x); o[1] = f2bf(x.y); o[2] = f2bf(x.z); o[3] = f2bf(x.w);
    o[4] = f2bf(y.x); o[5] = f2bf(y.y); o[6] = f2bf(y.z); o[7] = f2bf(y.w);
    *(v8us*)&out[i] = o;
}

// ---- projections (fp32 VALU, 16 rows/block, grid.y selects f1/f2) ----
__global__ __launch_bounds__(256) void proj_relu16(const float* __restrict__ F1,
                                                   const float* __restrict__ F2,
                                                   const float* __restrict__ W,
                                                   const float* __restrict__ bias,
                                                   float* __restrict__ H) {
    __shared__ float fr[16][256];
    const float* F = blockIdx.y ? F2 : F1;
    float* Ho = H + (size_t)blockIdx.y * BROWS * DIMK;
    const int r0 = blockIdx.x << 4, j = threadIdx.x;
#pragma unroll
    for (int r = 0; r < 16; ++r) fr[r][j] = F[(size_t)(r0 + r) * DIMK + j];
    __syncthreads();
    float acc[16];
    const float bj = bias[j];
#pragma unroll
    for (int r = 0; r < 16; ++r) acc[r] = bj;
    for (int k = 0; k < DIMK; k += 4) {
        const float w0 = W[(k + 0) * DIMK + j];
        const float w1 = W[(k + 1) * DIMK + j];
        const float w2 = W[(k + 2) * DIMK + j];
        const float w3 = W[(k + 3) * DIMK + j];
#pragma unroll
        for (int r = 0; r < 16; ++r) {
            float4 f = *(const float4*)&fr[r][k];
            acc[r] = fmaf(f.x, w0, acc[r]);
            acc[r] = fmaf(f.y, w1, acc[r]);
            acc[r] = fmaf(f.z, w2, acc[r]);
            acc[r] = fmaf(f.w, w3, acc[r]);
        }
    }
#pragma unroll
    for (int r = 0; r < 16; ++r)
        Ho[(size_t)(r0 + r) * DIMK + j] = acc[r] > 0.f ? acc[r] : 0.f;
}

__global__ __launch_bounds__(256) void proj_norm16(const float* __restrict__ H,
                                                   const float* __restrict__ W,
                                                   const float* __restrict__ bias,
                                                   ushort_t* __restrict__ P) {
    __shared__ float hr[16][256];
    __shared__ float partial[4][16];
    const float* Hi = H + (size_t)blockIdx.y * BROWS * DIMK;
    ushort_t* Po = P + (size_t)blockIdx.y * BROWS * DIMK;
    const int r0 = blockIdx.x << 4, j = threadIdx.x;
    const int w = j >> 6, l = j & 63;
#pragma unroll
    for (int r = 0; r < 16; ++r) hr[r][j] = Hi[(size_t)(r0 + r) * DIMK + j];
    __syncthreads();
    float acc[16];
    const float bj = bias[j];
#pragma unroll
    for (int r = 0; r < 16; ++r) acc[r] = bj;
    for (int k = 0; k < DIMK; k += 4) {
        const float w0 = W[(k + 0) * DIMK + j];
        const float w1 = W[(k + 1) * DIMK + j];
        const float w2 = W[(k + 2) * DIMK + j];
        const float w3 = W[(k + 3) * DIMK + j];
#pragma unroll
        for (int r = 0; r < 16; ++r) {
            float4 f = *(const float4*)&hr[r][k];
            acc[r] = fmaf(f.x, w0, acc[r]);
            acc[r] = fmaf(f.y, w1, acc[r]);
            acc[r] = fmaf(f.z, w2, acc[r]);
            acc[r] = fmaf(f.w, w3, acc[r]);
        }
    }
#pragma unroll
    for (int r = 0; r < 16; ++r) {
        float s = acc[r] * acc[r];
        s += __shfl_xor(s, 1);  s += __shfl_xor(s, 2);
        s += __shfl_xor(s, 4);  s += __shfl_xor(s, 8);
        s += __shfl_xor(s, 16); s += __shfl_xor(s, 32);
        if (l == 0) partial[w][r] = s;
    }
    __syncthreads();
#pragma unroll
    for (int r = 0; r < 16; ++r) {
        const float tot = partial[0][r] + partial[1][r] + partial[2][r] + partial[3][r];
        const float inv = 1.f / fmaxf(sqrtf(tot), 1e-12f);
        Po[(size_t)(r0 + r) * DIMK + j] = f2bf(acc[r] * inv);
    }
}

// stage one 512x32 bf16 B tile (64B rows). LDS dest linear; source pre-swizzled so
// physical slot s of row rr holds logical kslot s ^ ((rr>>1)&3).
__device__ __forceinline__ void stageB(const ushort_t* __restrict__ B, int colbase, int kk,
                                       ushort_t* dst, int w, int l) {
#pragma unroll
    for (int i = 0; i < 4; ++i) {
        const int blk = (w << 2) + i;                 // 32 blocks of 16 rows
        const int rr = (blk << 4) + (l >> 2);
        const int kslot = (l & 3) ^ ((l >> 3) & 3);   // == (l&3) ^ ((rr>>1)&3)
        GLOAD(&B[(size_t)(colbase + rr) * DIMK + (kk << 5) + (kslot << 3)],
              &dst[blk << 9]);
    }
}

// read 8 B fragments (col rows of this wave) from a 512x32 buffer
__device__ __forceinline__ void readB(v8bf* bv, const ushort_t* bufr, int wc, int l) {
#pragma unroll
    for (int nj = 0; nj < 8; ++nj) {
        const int row = (wc << 7) + (nj << 4) + (l & 15);
        const int phys = (l >> 4) ^ ((row >> 1) & 3);
        bv[nj] = *(const v8bf*)&bufr[(row << 5) + (phys << 3)];
    }
}

// ---- frag-pipelined A-hoisted GEMM, 512 thr (8 waves 2Mx4N), block tile 128x512
// MODE 0: fused argmax (A=Pcat[8192], B=Q)   MODE 1: exp-sum rows+cols+diag
template <int MODE, int NT>
__global__ __launch_bounds__(512, 1) void mfma_pipe(const ushort_t* __restrict__ Abase,
                                                    const ushort_t* __restrict__ Bbase,
                                                    u64_t* __restrict__ packed,
                                                    float* __restrict__ sums,
                                                    float* __restrict__ diag) {
    __shared__ __align__(16) ushort_t Alds[128 * 256];     // 64 KB, staged once
    __shared__ __align__(16) ushort_t Blds[2][512 * 32];   // 2 x 32 KB dbuf
    const int tid = threadIdx.x;
    const int w = tid >> 6, l = tid & 63;
    const int wr = w >> 2, wc = w & 3;   // 2M x 4N waves, wave tile 64x128
    constexpr int NP = NT * 8;           // total 32-k phases

    int row0, col00;
    const ushort_t* A;
    const ushort_t* B;
    float* sr = nullptr; float* sc = nullptr; float* dg = nullptr;
    if (MODE == 0) {
        const int bid = blockIdx.x;
        const int xcd = bid & 7, grp = bid >> 3;
        row0 = ((((xcd & 1) << 5) | grp) << 7);   // 64 row-groups of 128
        col00 = (xcd >> 1) << 13;                 // 4 col chunks of 8192, XCD-pinned
        A = Abase; B = Bbase;
    } else {
        const int z = blockIdx.z;
        row0 = (int)blockIdx.y << 7;
        col00 = (int)blockIdx.x << 10;
        A = Abase + (size_t)z * BROWS * DIMK;
        B = Bbase + (size_t)(1 - z) * BROWS * DIMK;
        sr = sums + (size_t)(2 * z) * BROWS;
        sc = sums + (size_t)(2 * z + 1) * BROWS;
        dg = diag + (size_t)z * BROWS;
    }

    // ---- prologue: A panel (once) + B0,B1; then frB(0) into regs; then B2
#pragma unroll
    for (int i = 0; i < 8; ++i) {
        const int row = (((w << 3) + i) << 1) + (l >> 5);
        const int kslot = (l & 31) ^ (row & 7);
        GLOAD(&A[(size_t)(row0 + row) * DIMK + (kslot << 3)], &Alds[(((w << 3) + i) << 9)]);
    }
    stageB(B, col00, 0, &Blds[0][0], w, l);
    stageB(B, col00, 1, &Blds[1][0], w, l);
    asm volatile("s_waitcnt vmcnt(4)" ::: "memory");   // A + B0 landed
    __builtin_amdgcn_s_barrier();

    v8bf bv[2][8];
    readB(bv[0], &Blds[0][0], wc, l);
    asm volatile("s_waitcnt lgkmcnt(0)" ::: "memory");
    __builtin_amdgcn_sched_barrier(0);
    __builtin_amdgcn_s_barrier();
    stageB(B, col00, 2, &Blds[0][0], w, l);            // B2 -> buf0 (freed)
    asm volatile("s_waitcnt vmcnt(4)" ::: "memory");   // B1 landed
    __builtin_amdgcn_s_barrier();

    float vbest[4][4];
    int cbest[4][4];
    if (MODE == 0) {
#pragma unroll
        for (int a = 0; a < 4; ++a)
#pragma unroll
            for (int r = 0; r < 4; ++r) { vbest[a][r] = -3e38f; cbest[a][r] = 0; }
    }

    for (int t = 0; t < NT; ++t) {
        const v4f vzero = {0.f, 0.f, 0.f, 0.f};
        v4f acc[4][8];
#pragma unroll
        for (int a = 0; a < 4; ++a)
#pragma unroll
            for (int b = 0; b < 8; ++b) acc[a][b] = vzero;

#pragma unroll
        for (int kk = 0; kk < 8; ++kk) {
            const int p = (t << 3) + kk;
            // frA(p): k-slice kk from resident A panel
            v8bf av[4];
#pragma unroll
            for (int mi = 0; mi < 4; ++mi) {
                const int row = (wr << 6) + (mi << 4) + (l & 15);
                const int phys = ((kk << 2) + (l >> 4)) ^ (row & 7);
                av[mi] = *(const v8bf*)&Alds[(row << 8) + (phys << 3)];
            }
            // frB(p+1): prefetch next phase's B frags (overlaps MFMA below)
            if (p + 1 < NP) readB(bv[(kk + 1) & 1], &Blds[(kk + 1) & 1][0], wc, l);
            __builtin_amdgcn_sched_barrier(0);   // pin reads above the MFMA cluster
            __builtin_amdgcn_s_setprio(1);
#pragma unroll
            for (int mi = 0; mi < 4; ++mi)
#pragma unroll
                for (int nj = 0; nj < 8; ++nj)
                    acc[mi][nj] = __builtin_amdgcn_mfma_f32_16x16x32_bf16(
                        av[mi], bv[kk & 1][nj], acc[mi][nj], 0, 0, 0);
            __builtin_amdgcn_s_setprio(0);
            asm volatile("s_waitcnt lgkmcnt(0)" ::: "memory");   // all reads of buf[(p+1)&1] done
            __builtin_amdgcn_sched_barrier(0);
            __builtin_amdgcn_s_barrier();        // all waves done reading -> buffer free
            if (p + 3 < NP) {
                const int k3 = p + 3;
                stageB(B, col00 + ((k3 >> 3) << 9), k3 & 7, &Blds[k3 & 1][0], w, l);
                asm volatile("s_waitcnt vmcnt(4)" ::: "memory");  // B(p+2) landed
            } else {
                asm volatile("s_waitcnt vmcnt(0)" ::: "memory");  // tail drain
            }
            __builtin_amdgcn_s_barrier();        // staged data visible to all
        }

        // ---- per-tile epilogue
        const int cb = col00 + (t << 9) + (wc << 7);
        if (MODE == 0) {
#pragma unroll
            for (int mi = 0; mi < 4; ++mi)
#pragma unroll
                for (int r = 0; r < 4; ++r) {
                    float v = acc[mi][0][r]; int c = cb;
#pragma unroll
                    for (int nj = 1; nj < 8; ++nj)
                        if (acc[mi][nj][r] > v) { v = acc[mi][nj][r]; c = cb + (nj << 4); }
                    if (v > vbest[mi][r]) { vbest[mi][r] = v; cbest[mi][r] = c; }
                }
        } else {
            const int rb = row0 + (wr << 6);
#pragma unroll
            for (int mi = 0; mi < 4; ++mi)
#pragma unroll
                for (int nj = 0; nj < 8; ++nj)
                    if (rb + (mi << 4) == cb + (nj << 4)) {
#pragma unroll
                        for (int r = 0; r < 4; ++r) {
                            const int rr = ((l >> 4) << 2) + r;
                            if ((l & 15) == rr) dg[rb + (mi << 4) + rr] = acc[mi][nj][r] * 10.0f;
                        }
                    }
#pragma unroll
            for (int mi = 0; mi < 4; ++mi)
#pragma unroll
                for (int nj = 0; nj < 8; ++nj) {
                    v4f tv = acc[mi][nj];
                    tv[0] = exp2f(tv[0] * EXPSCALE);
                    tv[1] = exp2f(tv[1] * EXPSCALE);
                    tv[2] = exp2f(tv[2] * EXPSCALE);
                    tv[3] = exp2f(tv[3] * EXPSCALE);
                    acc[mi][nj] = tv;
                }
#pragma unroll
            for (int mi = 0; mi < 4; ++mi)
#pragma unroll
                for (int r = 0; r < 4; ++r) {
                    float s = 0.f;
#pragma unroll
                    for (int nj = 0; nj < 8; ++nj) s += acc[mi][nj][r];
                    s += __shfl_xor(s, 1); s += __shfl_xor(s, 2);
                    s += __shfl_xor(s, 4); s += __shfl_xor(s, 8);
                    if ((l & 15) == 0)
                        atomicAdd(&sr[rb + (mi << 4) + ((l >> 4) << 2) + r], s);
                }
#pragma unroll
            for (int nj = 0; nj < 8; ++nj) {
                float s = 0.f;
#pragma unroll
                for (int mi = 0; mi < 4; ++mi)
#pragma unroll
                    for (int r = 0; r < 4; ++r) s += acc[mi][nj][r];
                s += __shfl_xor(s, 16); s += __shfl_xor(s, 32);
                if (l < 16) atomicAdd(&sc[cb + (nj << 4) + l], s);
            }
        }
    }

    if (MODE == 0) {
#pragma unroll
        for (int mi = 0; mi < 4; ++mi)
#pragma unroll
            for (int r = 0; r < 4; ++r) {
                const unsigned col = (unsigned)(cbest[mi][r] + (l & 15));
                u64_t pk = ((u64_t)enc_f32(vbest[mi][r]) << 32) | (u64_t)(0xFFFFFFFFu - col);
#pragma unroll
                for (int off = 1; off < 16; off <<= 1) {
                    u64_t o = shfl_xor_u64(pk, off);
                    if (o > pk) pk = o;
                }
                if ((l & 15) == 0)
                    atomicMax(&packed[row0 + (wr << 6) + (mi << 4) + ((l >> 4) << 2) + r], pk);
            }
    }
}

// ---- small epilogue kernels ----
__global__ __launch_bounds__(256) void gather_bf(const u64_t* __restrict__ packed,
                                                 const ushort_t* __restrict__ qb,
                                                 ushort_t* __restrict__ nn) {
    const int i = blockIdx.x, j = threadIdx.x;
    const unsigned idx = 0xFFFFFFFFu - (unsigned)(packed[i] & 0xFFFFFFFFull);
    nn[(size_t)i * DIMK + j] = qb[(size_t)idx * DIMK + j];
}

__global__ __launch_bounds__(256) void final_loss(const float* __restrict__ d1,
                                                  const float* __restrict__ d2,
                                                  const float* __restrict__ sr1,
                                                  const float* __restrict__ sc1,
                                                  const float* __restrict__ sr2,
                                                  const float* __restrict__ sc2,
                                                  float* __restrict__ out) {
    __shared__ float red[256];
    const int t = threadIdx.x;
    float acc = 0.f;
    for (int i = t; i < BROWS; i += 256) {
        acc += 2.f * (d1[i] + d2[i]) - logf(sr1[i]) - logf(sc1[i]) - logf(sr2[i]) - logf(sc2[i]);
    }
    red[t] = acc;
    __syncthreads();
    for (int s = 128; s > 0; s >>= 1) {
        if (t < s) red[t] += red[t + s];
        __syncthreads();
    }
    if (t == 0) out[0] = -red[0] / (4.0f * (float)BROWS);
}

extern "C" void kernel_launch(void* const* d_in, const int* in_sizes, int n_in,
                              void* d_out, int out_size, void* d_ws, size_t ws_size,
                              hipStream_t stream) {
    const float* f1 = (const float*)d_in[0];
    const float* f2 = (const float*)d_in[1];
    const float* W1 = (const float*)d_in[2];
    const float* b1 = (const float*)d_in[3];
    const float* W2 = (const float*)d_in[4];
    const float* b2 = (const float*)d_in[5];
    const float* queue = (const float*)d_in[6];
    float* out = (float*)d_out;

    char* ws = (char*)d_ws;
    float* h       = (float*)ws;                           // 8 MB (both halves)
    ushort_t* pcat = (ushort_t*)(ws + (8ull << 20));       // 4 MB: p1 | p2
    ushort_t* nncat= (ushort_t*)(ws + (12ull << 20));      // 4 MB: nn1 | nn2
    ushort_t* qb   = (ushort_t*)(ws + (16ull << 20));      // 16 MB
    u64_t* packed  = (u64_t*)(ws + (32ull << 20));         // 64 KB (8192)
    float* sums    = (float*)(ws + (32ull << 20) + (64ull << 10));   // 64 KB
    float* diag    = (float*)(ws + (32ull << 20) + (128ull << 10));  // 32 KB

    hipMemsetAsync(packed, 0, (128ull << 10), stream);

    conv_bf16<<<(QN * DIMK) / 2048, 256, 0, stream>>>(queue, qb);

    dim3 gp(BROWS / 16, 2);
    proj_relu16<<<gp, 256, 0, stream>>>(f1, f2, W1, b1, h);
    proj_norm16<<<gp, 256, 0, stream>>>(h, W2, b2, pcat);

    mfma_pipe<0, 16><<<256, 512, 0, stream>>>(pcat, qb, packed, nullptr, nullptr);

    gather_bf<<<2 * BROWS, 256, 0, stream>>>(packed, qb, nncat);

    dim3 gl(4, 32, 2);
    mfma_pipe<1, 2><<<gl, 512, 0, stream>>>(nncat, pcat, nullptr, sums, diag);

    final_loss<<<1, 256, 0, stream>>>(diag, diag + BROWS,
                                      sums, sums + BROWS, sums + 2 * BROWS, sums + 3 * BROWS,
                                      out);
}

// Round 5
// 357.959 us; speedup vs baseline: 1.2941x; 1.2941x over previous
//
#include <hip/hip_runtime.h>

typedef unsigned short ushort_t;
typedef unsigned long long u64_t;
typedef __attribute__((ext_vector_type(8))) short v8bf;
typedef __attribute__((ext_vector_type(8))) unsigned short v8us;
typedef __attribute__((ext_vector_type(4))) float v4f;

#define BROWS 4096
#define DIMK 256
#define QN 32768
#define EXPSCALE 14.426950408889634f   // 10 * log2(e)

__device__ __forceinline__ ushort_t f2bf(float f) {
    unsigned u = __float_as_uint(f);
    return (ushort_t)((u + 0x7FFFu + ((u >> 16) & 1u)) >> 16);   // RNE
}
__device__ __forceinline__ unsigned enc_f32(float f) {
    unsigned b = __float_as_uint(f);
    return b ^ ((unsigned)(((int)b) >> 31) | 0x80000000u);
}
__device__ __forceinline__ u64_t shfl_xor_u64(u64_t v, int off) {
    unsigned lo = (unsigned)(v & 0xFFFFFFFFull);
    unsigned hi = (unsigned)(v >> 32);
    lo = (unsigned)__shfl_xor((int)lo, off, 64);
    hi = (unsigned)__shfl_xor((int)hi, off, 64);
    return ((u64_t)hi << 32) | (u64_t)lo;
}
#define GLOAD(g, l_) __builtin_amdgcn_global_load_lds(                         \
    (const __attribute__((address_space(1))) void*)(g),                        \
    (__attribute__((address_space(3))) void*)(l_), 16, 0, 0)

// ---- bf16 conversion of the queue ----
__global__ __launch_bounds__(256) void conv_bf16(const float* __restrict__ in,
                                                 ushort_t* __restrict__ out) {
    const size_t i = ((size_t)blockIdx.x * 256 + threadIdx.x) * 8;
    float4 x = *(const float4*)&in[i];
    float4 y = *(const float4*)&in[i + 4];
    v8us o;
    o[0] = f2bf(x.x); o[1] = f2bf(x.y); o[2] = f2bf(x.z); o[3] = f2bf(x.w);
    o[4] = f2bf(y.x); o[5] = f2bf(y.y); o[6] = f2bf(y.z); o[7] = f2bf(y.w);
    *(v8us*)&out[i] = o;
}

// ---- projections (fp32 VALU, 16 rows/block, grid.y selects f1/f2) ----
__global__ __launch_bounds__(256) void proj_relu16(const float* __restrict__ F1,
                                                   const float* __restrict__ F2,
                                                   const float* __restrict__ W,
                                                   const float* __restrict__ bias,
                                                   float* __restrict__ H) {
    __shared__ float fr[16][256];
    const float* F = blockIdx.y ? F2 : F1;
    float* Ho = H + (size_t)blockIdx.y * BROWS * DIMK;
    const int r0 = blockIdx.x << 4, j = threadIdx.x;
#pragma unroll
    for (int r = 0; r < 16; ++r) fr[r][j] = F[(size_t)(r0 + r) * DIMK + j];
    __syncthreads();
    float acc[16];
    const float bj = bias[j];
#pragma unroll
    for (int r = 0; r < 16; ++r) acc[r] = bj;
    for (int k = 0; k < DIMK; k += 4) {
        const float w0 = W[(k + 0) * DIMK + j];
        const float w1 = W[(k + 1) * DIMK + j];
        const float w2 = W[(k + 2) * DIMK + j];
        const float w3 = W[(k + 3) * DIMK + j];
#pragma unroll
        for (int r = 0; r < 16; ++r) {
            float4 f = *(const float4*)&fr[r][k];
            acc[r] = fmaf(f.x, w0, acc[r]);
            acc[r] = fmaf(f.y, w1, acc[r]);
            acc[r] = fmaf(f.z, w2, acc[r]);
            acc[r] = fmaf(f.w, w3, acc[r]);
        }
    }
#pragma unroll
    for (int r = 0; r < 16; ++r)
        Ho[(size_t)(r0 + r) * DIMK + j] = acc[r] > 0.f ? acc[r] : 0.f;
}

__global__ __launch_bounds__(256) void proj_norm16(const float* __restrict__ H,
                                                   const float* __restrict__ W,
                                                   const float* __restrict__ bias,
                                                   ushort_t* __restrict__ P) {
    __shared__ float hr[16][256];
    __shared__ float partial[4][16];
    const float* Hi = H + (size_t)blockIdx.y * BROWS * DIMK;
    ushort_t* Po = P + (size_t)blockIdx.y * BROWS * DIMK;
    const int r0 = blockIdx.x << 4, j = threadIdx.x;
    const int w = j >> 6, l = j & 63;
#pragma unroll
    for (int r = 0; r < 16; ++r) hr[r][j] = Hi[(size_t)(r0 + r) * DIMK + j];
    __syncthreads();
    float acc[16];
    const float bj = bias[j];
#pragma unroll
    for (int r = 0; r < 16; ++r) acc[r] = bj;
    for (int k = 0; k < DIMK; k += 4) {
        const float w0 = W[(k + 0) * DIMK + j];
        const float w1 = W[(k + 1) * DIMK + j];
        const float w2 = W[(k + 2) * DIMK + j];
        const float w3 = W[(k + 3) * DIMK + j];
#pragma unroll
        for (int r = 0; r < 16; ++r) {
            float4 f = *(const float4*)&hr[r][k];
            acc[r] = fmaf(f.x, w0, acc[r]);
            acc[r] = fmaf(f.y, w1, acc[r]);
            acc[r] = fmaf(f.z, w2, acc[r]);
            acc[r] = fmaf(f.w, w3, acc[r]);
        }
    }
#pragma unroll
    for (int r = 0; r < 16; ++r) {
        float s = acc[r] * acc[r];
        s += __shfl_xor(s, 1);  s += __shfl_xor(s, 2);
        s += __shfl_xor(s, 4);  s += __shfl_xor(s, 8);
        s += __shfl_xor(s, 16); s += __shfl_xor(s, 32);
        if (l == 0) partial[w][r] = s;
    }
    __syncthreads();
#pragma unroll
    for (int r = 0; r < 16; ++r) {
        const float tot = partial[0][r] + partial[1][r] + partial[2][r] + partial[3][r];
        const float inv = 1.f / fmaxf(sqrtf(tot), 1e-12f);
        Po[(size_t)(r0 + r) * DIMK + j] = f2bf(acc[r] * inv);
    }
}

// ---- stage one 128x64 bf16 half-tile. LDS dest linear (gload_lds); global source
// pre-swizzled: physical k-octet s of row r holds logical octet s ^ (r&7).
__device__ __forceinline__ void stage_half(const ushort_t* __restrict__ M, int grow0,
                                           int kt, ushort_t* dst, int w, int l) {
#pragma unroll
    for (int j = 0; j < 2; ++j) {
        const int rowloc = (((j << 3) + w) << 3) + (l >> 3);
        const int oct = (l & 7) ^ ((l >> 3) & 7);
        GLOAD(&M[(size_t)(grow0 + rowloc) * DIMK + (kt << 6) + (oct << 3)],
              dst + ((((j << 3) + w)) << 9));
    }
}

// read one MFMA fragment from a 128x64 swizzled half (row = frow + lane&15)
__device__ __forceinline__ v8bf rdfrag(const ushort_t* half, int frow, int kk, int l) {
    const int row = frow + (l & 15);
    const int phys = ((kk << 2) + (l >> 4)) ^ (row & 7);
    return *(const v8bf*)&half[(row << 6) + (phys << 3)];
}

// ---- 256x256x256 MFMA block, 16-phase schedule (4 K-tiles x 4 C-quadrants)
// MODE 0: fused per-row argmax into packed[8][8192]; MODE 1: exp-sums + diag
template <int MODE>
__global__ __launch_bounds__(512, 1) void mfma8(const ushort_t* __restrict__ Abase,
                                                const ushort_t* __restrict__ Bbase,
                                                u64_t* __restrict__ packed,
                                                float* __restrict__ sums,
                                                float* __restrict__ diag) {
    __shared__ __align__(16) ushort_t Lds[2][4][8192];   // [dbuf][A0,A1,B0,B1][128x64]
    const int tid = threadIdx.x;
    const int w = tid >> 6, l = tid & 63;
    const int wr = w >> 2, wc = w & 3;     // 2M x 4N waves; wave tile 128x64

    int row0, col0, chunk = 0;
    const ushort_t* A; const ushort_t* B;
    float* sr = nullptr; float* sc = nullptr; float* dg = nullptr;
    if (MODE == 0) {
        // bijective XCD swizzle + 8x4 brick decode: XCD x owns col-blocks [16x,16x+16)
        const int bid = blockIdx.x;
        const int wgid = ((bid & 7) << 9) + (bid >> 3);
        const int brick = wgid >> 5, sub = wgid & 31;
        const int rowblk = ((brick & 3) << 3) + (sub & 7);     // 0..31
        const int colblk = ((brick >> 2) << 2) + (sub >> 3);   // 0..127
        row0 = rowblk << 8; col0 = colblk << 8;
        chunk = colblk >> 4;
        A = Abase; B = Bbase;
    } else {
        const int z = blockIdx.z;
        row0 = (int)blockIdx.y << 8;
        col0 = (int)blockIdx.x << 8;
        A = Abase + (size_t)z * BROWS * DIMK;
        B = Bbase + (size_t)(1 - z) * BROWS * DIMK;
        sr = sums + (size_t)(2 * z) * BROWS;
        sc = sums + (size_t)(2 * z + 1) * BROWS;
        dg = diag + (size_t)z * BROWS;
    }

    // ---- prologue: t0 all 4 halves + t1.B0,B1 (12 loads/thread); certify t0
    stage_half(A, row0,       0, &Lds[0][0][0], w, l);
    stage_half(A, row0 + 128, 0, &Lds[0][1][0], w, l);
    stage_half(B, col0,       0, &Lds[0][2][0], w, l);
    stage_half(B, col0 + 128, 0, &Lds[0][3][0], w, l);
    stage_half(B, col0,       1, &Lds[1][2][0], w, l);
    stage_half(B, col0 + 128, 1, &Lds[1][3][0], w, l);
    asm volatile("s_waitcnt vmcnt(4)" ::: "memory");   // first 8 loads (= t0) landed
    __builtin_amdgcn_s_barrier();

    v4f acc[8][4];
#pragma unroll
    for (int a = 0; a < 8; ++a)
#pragma unroll
        for (int b = 0; b < 4; ++b) acc[a][b] = (v4f){0.f, 0.f, 0.f, 0.f};
    v8bf av[4][2], bv[4][2];

#pragma unroll
    for (int T = 0; T < 4; ++T) {
        const int d = T & 1;
#pragma unroll
        for (int q = 0; q < 4; ++q) {
            const int mh = q >> 1, nh = q & 1;
            // (a) ds-read register subtile for THIS phase's MFMA
            if (q == 0) {
#pragma unroll
                for (int i = 0; i < 4; ++i) {
                    av[i][0] = rdfrag(&Lds[d][wr][0], i << 4, 0, l);
                    av[i][1] = rdfrag(&Lds[d][wr][0], i << 4, 1, l);
                    bv[i][0] = rdfrag(&Lds[d][2 + (wc >> 1)][0], ((wc & 1) << 6) + (i << 4), 0, l);
                    bv[i][1] = rdfrag(&Lds[d][2 + (wc >> 1)][0], ((wc & 1) << 6) + (i << 4), 1, l);
                }
            } else if (q == 2) {
#pragma unroll
                for (int i = 0; i < 4; ++i) {
                    av[i][0] = rdfrag(&Lds[d][wr][0], (4 + i) << 4, 0, l);
                    av[i][1] = rdfrag(&Lds[d][wr][0], (4 + i) << 4, 1, l);
                }
            }
            // (b) stage future halves into just-freed slots
            if (q == 0 && T < 3) {
                stage_half(A, row0,       T + 1, &Lds[(T + 1) & 1][0][0], w, l);
                stage_half(A, row0 + 128, T + 1, &Lds[(T + 1) & 1][1][0], w, l);
            } else if (q == 1 && T < 2) {
                stage_half(B, col0,       T + 2, &Lds[d][2][0], w, l);
            } else if (q == 2 && T < 2) {
                stage_half(B, col0 + 128, T + 2, &Lds[d][3][0], w, l);
            }
            __builtin_amdgcn_s_barrier();
            asm volatile("s_waitcnt lgkmcnt(0)" ::: "memory");
            __builtin_amdgcn_sched_barrier(0);
            __builtin_amdgcn_s_setprio(1);
#pragma unroll
            for (int mi = 0; mi < 4; ++mi)
#pragma unroll
                for (int nj = 0; nj < 2; ++nj)
#pragma unroll
                    for (int kk = 0; kk < 2; ++kk)
                        acc[(mh << 2) + mi][(nh << 1) + nj] =
                            __builtin_amdgcn_mfma_f32_16x16x32_bf16(
                                av[mi][kk], bv[(nh << 1) + nj][kk],
                                acc[(mh << 2) + mi][(nh << 1) + nj], 0, 0, 0);
            __builtin_amdgcn_s_setprio(0);
            __builtin_amdgcn_sched_barrier(0);
            if (q == 3) {
                if (T < 2)       asm volatile("s_waitcnt vmcnt(4)" ::: "memory");
                else if (T == 2) asm volatile("s_waitcnt vmcnt(0)" ::: "memory");
            }
            __builtin_amdgcn_s_barrier();
        }
    }

    if (MODE == 0) {
        // block-level argmax: wave reduce -> LDS [256 rows][4 wavecols] -> 1 atomic/row
        u64_t* red = (u64_t*)&Lds[0][0][0];
#pragma unroll
        for (int mi = 0; mi < 8; ++mi)
#pragma unroll
            for (int r = 0; r < 4; ++r) {
                float v = acc[mi][0][r]; int c = 0;
#pragma unroll
                for (int nj = 1; nj < 4; ++nj)
                    if (acc[mi][nj][r] > v) { v = acc[mi][nj][r]; c = nj; }
                const unsigned col = (unsigned)(col0 + (wc << 6) + (c << 4) + (l & 15));
                u64_t pk = ((u64_t)enc_f32(v) << 32) | (u64_t)(0xFFFFFFFFu - col);
#pragma unroll
                for (int off = 1; off < 16; off <<= 1) {
                    u64_t o = shfl_xor_u64(pk, off);
                    if (o > pk) pk = o;
                }
                if ((l & 15) == 0) {
                    const int rloc = (wr << 7) + (mi << 4) + ((l >> 4) << 2) + r;
                    red[(rloc << 2) + wc] = pk;
                }
            }
        __builtin_amdgcn_s_barrier();
        if (tid < 256) {
            u64_t b = red[tid << 2];
#pragma unroll
            for (int c = 1; c < 4; ++c) {
                u64_t o = red[(tid << 2) + c];
                if (o > b) b = o;
            }
            atomicMax(&packed[(chunk << 13) + row0 + tid], b);
        }
    } else {
        // diag (raw scores, before exp)
        if (row0 == col0) {
#pragma unroll
            for (int mi = 0; mi < 8; ++mi)
#pragma unroll
                for (int nj = 0; nj < 4; ++nj)
                    if ((wr << 3) + mi == (wc << 2) + nj) {
#pragma unroll
                        for (int r = 0; r < 4; ++r) {
                            const int rr = ((l >> 4) << 2) + r;
                            if ((l & 15) == rr)
                                dg[row0 + (wr << 7) + (mi << 4) + rr] = acc[mi][nj][r] * 10.0f;
                        }
                    }
        }
#pragma unroll
        for (int mi = 0; mi < 8; ++mi)
#pragma unroll
            for (int nj = 0; nj < 4; ++nj) {
                v4f tv = acc[mi][nj];
                tv[0] = exp2f(tv[0] * EXPSCALE);
                tv[1] = exp2f(tv[1] * EXPSCALE);
                tv[2] = exp2f(tv[2] * EXPSCALE);
                tv[3] = exp2f(tv[3] * EXPSCALE);
                acc[mi][nj] = tv;
            }
#pragma unroll
        for (int mi = 0; mi < 8; ++mi)
#pragma unroll
            for (int r = 0; r < 4; ++r) {
                float s = acc[mi][0][r] + acc[mi][1][r] + acc[mi][2][r] + acc[mi][3][r];
                s += __shfl_xor(s, 1); s += __shfl_xor(s, 2);
                s += __shfl_xor(s, 4); s += __shfl_xor(s, 8);
                if ((l & 15) == 0)
                    atomicAdd(&sr[row0 + (wr << 7) + (mi << 4) + ((l >> 4) << 2) + r], s);
            }
#pragma unroll
        for (int nj = 0; nj < 4; ++nj) {
            float s = 0.f;
#pragma unroll
            for (int mi = 0; mi < 8; ++mi)
#pragma unroll
                for (int r = 0; r < 4; ++r) s += acc[mi][nj][r];
            s += __shfl_xor(s, 16); s += __shfl_xor(s, 32);
            if (l < 16) atomicAdd(&sc[col0 + (wc << 6) + (nj << 4) + l], s);
        }
    }
}

// ---- reduce 8 col-chunk argmax candidates + gather queue row ----
__global__ __launch_bounds__(256) void gather_bf(const u64_t* __restrict__ packed,
                                                 const ushort_t* __restrict__ qb,
                                                 ushort_t* __restrict__ nn) {
    const int i = blockIdx.x, j = threadIdx.x;
    u64_t b = packed[i];
#pragma unroll
    for (int c = 1; c < 8; ++c) {
        u64_t o = packed[(c << 13) + i];
        if (o > b) b = o;
    }
    const unsigned idx = 0xFFFFFFFFu - (unsigned)(b & 0xFFFFFFFFull);
    nn[(size_t)i * DIMK + j] = qb[(size_t)idx * DIMK + j];
}

__global__ __launch_bounds__(256) void final_loss(const float* __restrict__ d1,
                                                  const float* __restrict__ d2,
                                                  const float* __restrict__ sr1,
                                                  const float* __restrict__ sc1,
                                                  const float* __restrict__ sr2,
                                                  const float* __restrict__ sc2,
                                                  float* __restrict__ out) {
    __shared__ float red[256];
    const int t = threadIdx.x;
    float acc = 0.f;
    for (int i = t; i < BROWS; i += 256) {
        acc += 2.f * (d1[i] + d2[i]) - logf(sr1[i]) - logf(sc1[i]) - logf(sr2[i]) - logf(sc2[i]);
    }
    red[t] = acc;
    __syncthreads();
    for (int s = 128; s > 0; s >>= 1) {
        if (t < s) red[t] += red[t + s];
        __syncthreads();
    }
    if (t == 0) out[0] = -red[0] / (4.0f * (float)BROWS);
}

extern "C" void kernel_launch(void* const* d_in, const int* in_sizes, int n_in,
                              void* d_out, int out_size, void* d_ws, size_t ws_size,
                              hipStream_t stream) {
    const float* f1 = (const float*)d_in[0];
    const float* f2 = (const float*)d_in[1];
    const float* W1 = (const float*)d_in[2];
    const float* b1 = (const float*)d_in[3];
    const float* W2 = (const float*)d_in[4];
    const float* b2 = (const float*)d_in[5];
    const float* queue = (const float*)d_in[6];
    float* out = (float*)d_out;

    char* ws = (char*)d_ws;
    float* h        = (float*)ws;                          // 8 MB (both halves)
    ushort_t* pcat  = (ushort_t*)(ws + (8ull << 20));      // 4 MB: p1 | p2
    ushort_t* nncat = (ushort_t*)(ws + (12ull << 20));     // 4 MB: nn1 | nn2
    ushort_t* qb    = (ushort_t*)(ws + (16ull << 20));     // 16 MB
    u64_t* packed   = (u64_t*)(ws + (32ull << 20));        // 512 KB: [8][8192]
    float* sums     = (float*)(ws + (32ull << 20) + (512ull << 10));  // 64 KB
    float* diag     = (float*)(ws + (32ull << 20) + (576ull << 10));  // 32 KB

    // zero atomic targets (packed argmax chunks + exp sums)
    hipMemsetAsync(packed, 0, (576ull << 10), stream);

    conv_bf16<<<(QN * DIMK) / 2048, 256, 0, stream>>>(queue, qb);

    dim3 gp(BROWS / 16, 2);
    proj_relu16<<<gp, 256, 0, stream>>>(f1, f2, W1, b1, h);
    proj_norm16<<<gp, 256, 0, stream>>>(h, W2, b2, pcat);

    mfma8<0><<<4096, 512, 0, stream>>>(pcat, qb, packed, nullptr, nullptr);

    gather_bf<<<2 * BROWS, 256, 0, stream>>>(packed, qb, nncat);

    dim3 gl(16, 16, 2);
    mfma8<1><<<gl, 512, 0, stream>>>(nncat, pcat, nullptr, sums, diag);

    final_loss<<<1, 256, 0, stream>>>(diag, diag + BROWS,
                                      sums, sums + BROWS, sums + 2 * BROWS, sums + 3 * BROWS,
                                      out);
}

// Round 6
// 340.927 us; speedup vs baseline: 1.3587x; 1.0500x over previous
//
#include <hip/hip_runtime.h>

typedef unsigned short ushort_t;
typedef unsigned long long u64_t;
typedef __attribute__((ext_vector_type(8))) short v8bf;
typedef __attribute__((ext_vector_type(8))) unsigned short v8us;
typedef __attribute__((ext_vector_type(4))) float v4f;

#define BROWS 4096
#define DIMK 256
#define QN 32768
#define EXPSCALE 14.426950408889634f   // 10 * log2(e)

__device__ __forceinline__ ushort_t f2bf(float f) {
    unsigned u = __float_as_uint(f);
    return (ushort_t)((u + 0x7FFFu + ((u >> 16) & 1u)) >> 16);   // RNE
}
__device__ __forceinline__ u64_t shfl_xor_u64(u64_t v, int off) {
    unsigned lo = (unsigned)(v & 0xFFFFFFFFull);
    unsigned hi = (unsigned)(v >> 32);
    lo = (unsigned)__shfl_xor((int)lo, off, 64);
    hi = (unsigned)__shfl_xor((int)hi, off, 64);
    return ((u64_t)hi << 32) | (u64_t)lo;
}
#define GLOAD(g, l_) __builtin_amdgcn_global_load_lds(                         \
    (const __attribute__((address_space(1))) void*)(g),                        \
    (__attribute__((address_space(3))) void*)(l_), 16, 0, 0)

// ---- bf16 conversion of the queue ----
__global__ __launch_bounds__(256) void conv_bf16(const float* __restrict__ in,
                                                 ushort_t* __restrict__ out) {
    const size_t i = ((size_t)blockIdx.x * 256 + threadIdx.x) * 8;
    float4 x = *(const float4*)&in[i];
    float4 y = *(const float4*)&in[i + 4];
    v8us o;
    o[0] = f2bf(x.x); o[1] = f2bf(x.y); o[2] = f2bf(x.z); o[3] = f2bf(x.w);
    o[4] = f2bf(y.x); o[5] = f2bf(y.y); o[6] = f2bf(y.z); o[7] = f2bf(y.w);
    *(v8us*)&out[i] = o;
}

// ---- projections (fp32 VALU, 16 rows/block, grid.y selects f1/f2) ----
__global__ __launch_bounds__(256) void proj_relu16(const float* __restrict__ F1,
                                                   const float* __restrict__ F2,
                                                   const float* __restrict__ W,
                                                   const float* __restrict__ bias,
                                                   float* __restrict__ H) {
    __shared__ float fr[16][256];
    const float* F = blockIdx.y ? F2 : F1;
    float* Ho = H + (size_t)blockIdx.y * BROWS * DIMK;
    const int r0 = blockIdx.x << 4, j = threadIdx.x;
#pragma unroll
    for (int r = 0; r < 16; ++r) fr[r][j] = F[(size_t)(r0 + r) * DIMK + j];
    __syncthreads();
    float acc[16];
    const float bj = bias[j];
#pragma unroll
    for (int r = 0; r < 16; ++r) acc[r] = bj;
    for (int k = 0; k < DIMK; k += 4) {
        const float w0 = W[(k + 0) * DIMK + j];
        const float w1 = W[(k + 1) * DIMK + j];
        const float w2 = W[(k + 2) * DIMK + j];
        const float w3 = W[(k + 3) * DIMK + j];
#pragma unroll
        for (int r = 0; r < 16; ++r) {
            float4 f = *(const float4*)&fr[r][k];
            acc[r] = fmaf(f.x, w0, acc[r]);
            acc[r] = fmaf(f.y, w1, acc[r]);
            acc[r] = fmaf(f.z, w2, acc[r]);
            acc[r] = fmaf(f.w, w3, acc[r]);
        }
    }
#pragma unroll
    for (int r = 0; r < 16; ++r)
        Ho[(size_t)(r0 + r) * DIMK + j] = acc[r] > 0.f ? acc[r] : 0.f;
}

__global__ __launch_bounds__(256) void proj_norm16(const float* __restrict__ H,
                                                   const float* __restrict__ W,
                                                   const float* __restrict__ bias,
                                                   ushort_t* __restrict__ P) {
    __shared__ float hr[16][256];
    __shared__ float partial[4][16];
    const float* Hi = H + (size_t)blockIdx.y * BROWS * DIMK;
    ushort_t* Po = P + (size_t)blockIdx.y * BROWS * DIMK;
    const int r0 = blockIdx.x << 4, j = threadIdx.x;
    const int w = j >> 6, l = j & 63;
#pragma unroll
    for (int r = 0; r < 16; ++r) hr[r][j] = Hi[(size_t)(r0 + r) * DIMK + j];
    __syncthreads();
    float acc[16];
    const float bj = bias[j];
#pragma unroll
    for (int r = 0; r < 16; ++r) acc[r] = bj;
    for (int k = 0; k < DIMK; k += 4) {
        const float w0 = W[(k + 0) * DIMK + j];
        const float w1 = W[(k + 1) * DIMK + j];
        const float w2 = W[(k + 2) * DIMK + j];
        const float w3 = W[(k + 3) * DIMK + j];
#pragma unroll
        for (int r = 0; r < 16; ++r) {
            float4 f = *(const float4*)&hr[r][k];
            acc[r] = fmaf(f.x, w0, acc[r]);
            acc[r] = fmaf(f.y, w1, acc[r]);
            acc[r] = fmaf(f.z, w2, acc[r]);
            acc[r] = fmaf(f.w, w3, acc[r]);
        }
    }
#pragma unroll
    for (int r = 0; r < 16; ++r) {
        float s = acc[r] * acc[r];
        s += __shfl_xor(s, 1);  s += __shfl_xor(s, 2);
        s += __shfl_xor(s, 4);  s += __shfl_xor(s, 8);
        s += __shfl_xor(s, 16); s += __shfl_xor(s, 32);
        if (l == 0) partial[w][r] = s;
    }
    __syncthreads();
#pragma unroll
    for (int r = 0; r < 16; ++r) {
        const float tot = partial[0][r] + partial[1][r] + partial[2][r] + partial[3][r];
        const float inv = 1.f / fmaxf(sqrtf(tot), 1e-12f);
        Po[(size_t)(r0 + r) * DIMK + j] = f2bf(acc[r] * inv);
    }
}

// ---- stage nch*32 rows x 64 k (bf16). LDS dest linear (gload_lds HW: base+lane*16);
// global source pre-swizzled: phys octet (l&7) holds logical octet (l&7)^(row&7).
__device__ __forceinline__ void stage(const ushort_t* __restrict__ M, int grow0,
                                      int kelem, ushort_t* lds, int w, int l, int nch) {
#pragma unroll
    for (int j = 0; j < 8; ++j) {
        if (j >= nch) break;
        const int row = (j << 5) + (w << 3) + (l >> 3);
        const int oct = (l & 7) ^ (l >> 3);
        GLOAD(&M[(size_t)(grow0 + row) * DIMK + kelem + (oct << 3)],
              lds + (j << 11) + (w << 9));
    }
}

// read one MFMA fragment from a swizzled [R][64] tile
__device__ __forceinline__ v8bf frag(const ushort_t* lds, int row, int ks) {
    const int phys = ks ^ (row & 7);
    return *(const v8bf*)&lds[(row << 6) + (phys << 3)];
}

// ---- R2-style 2-barrier t-loop GEMM. block 128x256, 4 waves (2Mx2N), wave 64x128.
// MODE 0: fused argmax over N-chunk (A=Pcat[8192], B=Q)  MODE 1: exp-sums + diag
template <int MODE, int NT>
__global__ __launch_bounds__(256, 2) void nn_lse(const ushort_t* __restrict__ Abase,
                                                 const ushort_t* __restrict__ Bbase,
                                                 u64_t* __restrict__ packed,
                                                 float* __restrict__ sums,
                                                 float* __restrict__ diag) {
    __shared__ __align__(16) ushort_t As[128 * 64];   // 16 KB
    __shared__ __align__(16) ushort_t Bs[256 * 64];   // 32 KB
    const int tid = threadIdx.x;
    const int w = tid >> 6, l = tid & 63;
    const int wr = w >> 1, wc = w & 1;   // wave tile 64 rows x 128 cols

    int arow0, chunkcol;
    const ushort_t* A; const ushort_t* B;
    float* sr = nullptr; float* sc = nullptr; float* dg = nullptr;
    if (MODE == 0) {
        const int bid = blockIdx.x;          // 1024 blocks
        const int xcd = bid & 7, i = bid >> 3;
        const int chunk = (xcd << 1) | (i >> 6);   // 16 chunks of 2048 cols, XCD-pinned
        arow0 = (i & 63) << 7;                      // 64 row-blocks of 128 (8192 rows)
        chunkcol = chunk << 11;
        A = Abase; B = Bbase;
    } else {
        const int z = blockIdx.z;
        arow0 = (int)blockIdx.y << 7;
        chunkcol = (int)blockIdx.x << 10;           // 4 chunks of 1024 cols
        A = Abase + (size_t)z * BROWS * DIMK;
        B = Bbase + (size_t)(1 - z) * BROWS * DIMK;
        sr = sums + (size_t)(2 * z) * BROWS;
        sc = sums + (size_t)(2 * z + 1) * BROWS;
        dg = diag + (size_t)z * BROWS;
    }

    unsigned wbest[4][4];
    int tbest[4][4];
    float rsum[4][4];
#pragma unroll
    for (int a = 0; a < 4; ++a)
#pragma unroll
        for (int r = 0; r < 4; ++r) { wbest[a][r] = 0u; tbest[a][r] = 0; rsum[a][r] = 0.f; }

    for (int t = 0; t < NT; ++t) {
        v4f acc[4][8];
        const float cinit = (MODE == 0) ? 2.0f : 0.0f;   // +2 bias -> positive, uint-monotone
#pragma unroll
        for (int a = 0; a < 4; ++a)
#pragma unroll
            for (int b = 0; b < 8; ++b) acc[a][b] = (v4f){cinit, cinit, cinit, cinit};

#pragma unroll
        for (int k0 = 0; k0 < 4; ++k0) {
            const int kelem = k0 << 6;
            stage(A, arow0, kelem, As, w, l, 4);
            stage(B, chunkcol + (t << 8), kelem, Bs, w, l, 8);
            __syncthreads();
#pragma unroll
            for (int hh = 0; hh < 2; ++hh) {
                const int ks = (hh << 2) + (l >> 4);
                v8bf av[4], bv[8];
#pragma unroll
                for (int mi = 0; mi < 4; ++mi)
                    av[mi] = frag(As, (wr << 6) + (mi << 4) + (l & 15), ks);
#pragma unroll
                for (int nj = 0; nj < 8; ++nj)
                    bv[nj] = frag(Bs, (wc << 7) + (nj << 4) + (l & 15), ks);
#pragma unroll
                for (int mi = 0; mi < 4; ++mi)
#pragma unroll
                    for (int nj = 0; nj < 8; ++nj)
                        acc[mi][nj] = __builtin_amdgcn_mfma_f32_16x16x32_bf16(
                            av[mi], bv[nj], acc[mi][nj], 0, 0, 0);
            }
            __syncthreads();
        }

        if (MODE == 0) {
            // packed running argmax: (bits(v+2) & ~7) | nj, uint-max; track t separately
#pragma unroll
            for (int mi = 0; mi < 4; ++mi)
#pragma unroll
                for (int r = 0; r < 4; ++r) {
                    unsigned m = __float_as_uint(acc[mi][0][r]) & 0xFFFFFFF8u;
#pragma unroll
                    for (int nj = 1; nj < 8; ++nj) {
                        unsigned c = (__float_as_uint(acc[mi][nj][r]) & 0xFFFFFFF8u) | (unsigned)nj;
                        m = c > m ? c : m;
                    }
                    if (m > wbest[mi][r]) { wbest[mi][r] = m; tbest[mi][r] = t; }
                }
        } else {
            const int cb = chunkcol + (t << 8);
            // diag from raw scores (before exp)
            if ((arow0 & 255) == 0 || 1) {
#pragma unroll
                for (int mi = 0; mi < 4; ++mi)
#pragma unroll
                    for (int nj = 0; nj < 8; ++nj) {
                        const int gr16 = arow0 + (wr << 6) + (mi << 4);
                        const int gc16 = cb + (wc << 7) + (nj << 4);
                        if (gr16 == gc16) {
#pragma unroll
                            for (int r = 0; r < 4; ++r) {
                                const int rr = ((l >> 4) << 2) + r;
                                if ((l & 15) == rr) dg[gr16 + rr] = acc[mi][nj][r] * 10.0f;
                            }
                        }
                    }
            }
            // exp in place, accumulate row sums in regs, col sums via per-t atomic
#pragma unroll
            for (int mi = 0; mi < 4; ++mi)
#pragma unroll
                for (int nj = 0; nj < 8; ++nj) {
                    v4f tv = acc[mi][nj];
                    tv[0] = exp2f(tv[0] * EXPSCALE);
                    tv[1] = exp2f(tv[1] * EXPSCALE);
                    tv[2] = exp2f(tv[2] * EXPSCALE);
                    tv[3] = exp2f(tv[3] * EXPSCALE);
                    acc[mi][nj] = tv;
                }
#pragma unroll
            for (int mi = 0; mi < 4; ++mi)
#pragma unroll
                for (int r = 0; r < 4; ++r) {
                    float s = 0.f;
#pragma unroll
                    for (int nj = 0; nj < 8; ++nj) s += acc[mi][nj][r];
                    rsum[mi][r] += s;
                }
#pragma unroll
            for (int nj = 0; nj < 8; ++nj) {
                float s = 0.f;
#pragma unroll
                for (int mi = 0; mi < 4; ++mi)
#pragma unroll
                    for (int r = 0; r < 4; ++r) s += acc[mi][nj][r];
                s += __shfl_xor(s, 16); s += __shfl_xor(s, 32);
                if (l < 16) atomicAdd(&sc[cb + (wc << 7) + (nj << 4) + l], s);
            }
        }
    }

    if (MODE == 0) {
#pragma unroll
        for (int mi = 0; mi < 4; ++mi)
#pragma unroll
            for (int r = 0; r < 4; ++r) {
                const unsigned wb = wbest[mi][r];
                const unsigned col = (unsigned)(chunkcol + (tbest[mi][r] << 8) + (wc << 7) +
                                                (int)((wb & 7u) << 4)) + (l & 15);
                u64_t pk = ((u64_t)wb << 32) | (u64_t)(0xFFFFFFFFu - col);
#pragma unroll
                for (int off = 1; off < 16; off <<= 1) {
                    u64_t o = shfl_xor_u64(pk, off);
                    if (o > pk) pk = o;
                }
                if ((l & 15) == 0)
                    atomicMax(&packed[arow0 + (wr << 6) + (mi << 4) + ((l >> 4) << 2) + r], pk);
            }
    } else {
#pragma unroll
        for (int mi = 0; mi < 4; ++mi)
#pragma unroll
            for (int r = 0; r < 4; ++r) {
                float s = rsum[mi][r];
                s += __shfl_xor(s, 1); s += __shfl_xor(s, 2);
                s += __shfl_xor(s, 4); s += __shfl_xor(s, 8);
                if ((l & 15) == 0)
                    atomicAdd(&sr[arow0 + (wr << 6) + (mi << 4) + ((l >> 4) << 2) + r], s);
            }
    }
}

// ---- gather nn rows (grid-stride) ----
__global__ __launch_bounds__(256) void gather_bf(const u64_t* __restrict__ packed,
                                                 const ushort_t* __restrict__ qb,
                                                 ushort_t* __restrict__ nn) {
    const int j = threadIdx.x;
    for (int i = blockIdx.x; i < 2 * BROWS; i += (int)gridDim.x) {
        const unsigned idx = 0xFFFFFFFFu - (unsigned)(packed[i] & 0xFFFFFFFFull);
        nn[(size_t)i * DIMK + j] = qb[(size_t)idx * DIMK + j];
    }
}

__global__ __launch_bounds__(256) void final_loss(const float* __restrict__ d1,
                                                  const float* __restrict__ d2,
                                                  const float* __restrict__ sr1,
                                                  const float* __restrict__ sc1,
                                                  const float* __restrict__ sr2,
                                                  const float* __restrict__ sc2,
                                                  float* __restrict__ out) {
    __shared__ float red[256];
    const int t = threadIdx.x;
    float acc = 0.f;
    for (int i = t; i < BROWS; i += 256) {
        acc += 2.f * (d1[i] + d2[i]) - logf(sr1[i]) - logf(sc1[i]) - logf(sr2[i]) - logf(sc2[i]);
    }
    red[t] = acc;
    __syncthreads();
    for (int s = 128; s > 0; s >>= 1) {
        if (t < s) red[t] += red[t + s];
        __syncthreads();
    }
    if (t == 0) out[0] = -red[0] / (4.0f * (float)BROWS);
}

extern "C" void kernel_launch(void* const* d_in, const int* in_sizes, int n_in,
                              void* d_out, int out_size, void* d_ws, size_t ws_size,
                              hipStream_t stream) {
    const float* f1 = (const float*)d_in[0];
    const float* f2 = (const float*)d_in[1];
    const float* W1 = (const float*)d_in[2];
    const float* b1 = (const float*)d_in[3];
    const float* W2 = (const float*)d_in[4];
    const float* b2 = (const float*)d_in[5];
    const float* queue = (const float*)d_in[6];
    float* out = (float*)d_out;

    char* ws = (char*)d_ws;
    float* h        = (float*)ws;                          // 8 MB (both halves)
    ushort_t* pcat  = (ushort_t*)(ws + (8ull << 20));      // 4 MB: p1 | p2
    ushort_t* nncat = (ushort_t*)(ws + (12ull << 20));     // 4 MB: nn1 | nn2
    ushort_t* qb    = (ushort_t*)(ws + (16ull << 20));     // 16 MB
    u64_t* packed   = (u64_t*)(ws + (32ull << 20));        // 64 KB (8192 rows)
    float* sums     = (float*)(ws + (32ull << 20) + (64ull << 10));   // 64 KB
    float* diag     = (float*)(ws + (32ull << 20) + (128ull << 10));  // 32 KB

    // zero atomic targets (packed argmax + exp sums)
    hipMemsetAsync(packed, 0, (128ull << 10), stream);

    conv_bf16<<<(QN * DIMK) / 2048, 256, 0, stream>>>(queue, qb);

    dim3 gp(BROWS / 16, 2);
    proj_relu16<<<gp, 256, 0, stream>>>(f1, f2, W1, b1, h);
    proj_norm16<<<gp, 256, 0, stream>>>(h, W2, b2, pcat);

    nn_lse<0, 8><<<1024, 256, 0, stream>>>(pcat, qb, packed, nullptr, nullptr);

    gather_bf<<<256, 256, 0, stream>>>(packed, qb, nncat);

    dim3 gl(4, 32, 2);
    nn_lse<1, 4><<<gl, 256, 0, stream>>>(nncat, pcat, nullptr, sums, diag);

    final_loss<<<1, 256, 0, stream>>>(diag, diag + BROWS,
                                      sums, sums + BROWS, sums + 2 * BROWS, sums + 3 * BROWS,
                                      out);
}